// Round 6
// baseline (673.008 us; speedup 1.0000x reference)
//
#include <hip/hip_runtime.h>
#include <hip/hip_bf16.h>

#define B_   64
#define P_   100
#define N_   1000
#define EMB_ 128
#define HEAD_ 8
#define QKV_ 16
#define QT   4          // queries per tile

constexpr double kTwoPowNeg18 = 3.814697265625e-06; // 2^-18 exact
constexpr double kA_d = 1.0 / (1.0 + kTwoPowNeg18);

// ---------------------------------------------------------------------------
// Kernel 1: K2/V2 = heads(en @ Wk/Wv) in [b][h][n][16] layout.
// 32 rows per block, 256 threads. e-operand read as b128 broadcasts.
// ---------------------------------------------------------------------------
__global__ __launch_bounds__(256) void kv_proj(
    const float* __restrict__ en, const float* __restrict__ Wk,
    const float* __restrict__ Wv, float* __restrict__ K2, float* __restrict__ V2)
{
    __shared__ __align__(16) float e_s[32][128];
    const int t = threadIdx.x;
    const int j = t & 127;
    const int half = t >> 7;
    const int r0 = blockIdx.x * 32;

    {
        const float4* src = (const float4*)(en + (size_t)r0 * 128);
        float4* dst = (float4*)&e_s[0][0];
        #pragma unroll
        for (int k = 0; k < 4; ++k) dst[t + 256 * k] = src[t + 256 * k];
    }
    __syncthreads();

    float ak[16], av[16];
    #pragma unroll
    for (int r = 0; r < 16; ++r) { ak[r] = 0.f; av[r] = 0.f; }

    const int rb = half * 16;
    for (int i4 = 0; i4 < 32; ++i4) {
        float wk4[4], wv4[4];
        #pragma unroll
        for (int c = 0; c < 4; ++c) {
            wk4[c] = Wk[(4 * i4 + c) * 128 + j];
            wv4[c] = Wv[(4 * i4 + c) * 128 + j];
        }
        #pragma unroll
        for (int r = 0; r < 16; ++r) {
            const float4 e4 = *(const float4*)&e_s[rb + r][4 * i4];
            ak[r] = fmaf(e4.x, wk4[0], fmaf(e4.y, wk4[1],
                    fmaf(e4.z, wk4[2], fmaf(e4.w, wk4[3], ak[r]))));
            av[r] = fmaf(e4.x, wv4[0], fmaf(e4.y, wv4[1],
                    fmaf(e4.z, wv4[2], fmaf(e4.w, wv4[3], av[r]))));
        }
    }

    const int h = j >> 4, d = j & 15;
    #pragma unroll
    for (int r = 0; r < 16; ++r) {
        const int row = r0 + rb + r;
        const int bb = row / N_;
        const int n = row - bb * N_;
        const size_t idx = ((size_t)(bb * HEAD_ + h) * N_ + n) * 16 + d;
        K2[idx] = ak[r];
        V2[idx] = av[r];
    }
}

// ---------------------------------------------------------------------------
// Kernel 2: Q = [eln | load | time] @ Wq   (rows = B*P = 6400, Wq is 130x128)
// ---------------------------------------------------------------------------
__global__ __launch_bounds__(128) void q_proj(
    const float* __restrict__ eln, const float* __restrict__ load_,
    const float* __restrict__ time_, const float* __restrict__ Wq,
    float* __restrict__ Q)
{
    __shared__ __align__(16) float e_s[8][132];
    const int j  = threadIdx.x;
    const int r0 = blockIdx.x * 8;

    #pragma unroll
    for (int r = 0; r < 8; ++r) {
        const int row = r0 + r;
        e_s[r][j] = eln[(size_t)row * 128 + j];
        if (j == 0) {
            e_s[r][128] = load_[row];
            e_s[r][129] = time_[row];
        }
    }
    __syncthreads();

    float a[8];
    #pragma unroll
    for (int r = 0; r < 8; ++r) a[r] = 0.f;

    for (int i4 = 0; i4 < 32; ++i4) {
        float w4[4];
        #pragma unroll
        for (int c = 0; c < 4; ++c) w4[c] = Wq[(4 * i4 + c) * 128 + j];
        #pragma unroll
        for (int r = 0; r < 8; ++r) {
            const float4 e4 = *(const float4*)&e_s[r][4 * i4];
            a[r] = fmaf(e4.x, w4[0], fmaf(e4.y, w4[1],
                   fmaf(e4.z, w4[2], fmaf(e4.w, w4[3], a[r]))));
        }
    }
    #pragma unroll
    for (int i = 128; i < 130; ++i) {
        const float w = Wq[i * 128 + j];
        #pragma unroll
        for (int r = 0; r < 8; ++r)
            a[r] = fmaf(e_s[r][i], w, a[r]);
    }

    #pragma unroll
    for (int r = 0; r < 8; ++r)
        Q[(size_t)(r0 + r) * 128 + j] = a[r];
}

// ---------------------------------------------------------------------------
// Kernel 3a: per-head attention. grid = B * HEAD * (P/QT) = 12800 blocks.
// XCD swizzle: physical = h + 8*(pt + 25*b)  => XCD (i%8) = h, b-major order,
// so the 25 blocks sharing one (b,h) K/V panel co-locate on one XCD's L2.
// ---------------------------------------------------------------------------
__global__ __launch_bounds__(256) void attn_heads(
    const float* __restrict__ K2, const float* __restrict__ V2,
    const float* __restrict__ Q, const float* __restrict__ ninf,
    float* __restrict__ out_g)
{
    __shared__ __align__(16) float sc[QT][1008];
    __shared__ __align__(16) float q_s[QT][16];
    __shared__ __align__(16) float part_s[4][QT][16];
    __shared__ float invden_s[QT];

    const int blk = blockIdx.x;
    const int h   = blk & 7;
    const int j9  = blk >> 3;          // 0..1599
    const int pt  = j9 % 25;
    const int b   = j9 / 25;
    const int bp0 = b * P_ + pt * QT;
    const int t    = threadIdx.x;
    const int lane = t & 63;
    const int wv   = t >> 6;

    if (t < 64) q_s[t >> 4][t & 15] =
        Q[(size_t)(bp0 + (t >> 4)) * 128 + h * 16 + (t & 15)];
    __syncthreads();

    float qr[QT][16];
    #pragma unroll
    for (int q = 0; q < QT; ++q)
        #pragma unroll
        for (int c = 0; c < 4; ++c)
            *(float4*)&qr[q][4 * c] = *(const float4*)&q_s[q][4 * c];

    // hoist masks for this thread's n's into registers
    const float* nf0 = ninf + (size_t)bp0 * N_;
    float msk[QT][4];
    #pragma unroll
    for (int i = 0; i < 4; ++i) {
        const int n = t + 256 * i;
        if (n < N_) {
            #pragma unroll
            for (int q = 0; q < QT; ++q) msk[q][i] = nf0[q * N_ + n];
        }
    }

    // ---- scores ----
    const float* Kh = K2 + (size_t)(b * HEAD_ + h) * N_ * 16;
    #pragma unroll
    for (int i = 0; i < 4; ++i) {
        const int n = t + 256 * i;
        if (n < N_) {
            const float4* kr = (const float4*)(Kh + (size_t)n * 16);
            const float4 k0 = kr[0], k1 = kr[1], k2 = kr[2], k3 = kr[3];
            #pragma unroll
            for (int q = 0; q < QT; ++q) {
                float d = k0.x * qr[q][0]  + k0.y * qr[q][1]
                        + k0.z * qr[q][2]  + k0.w * qr[q][3]
                        + k1.x * qr[q][4]  + k1.y * qr[q][5]
                        + k1.z * qr[q][6]  + k1.w * qr[q][7]
                        + k2.x * qr[q][8]  + k2.y * qr[q][9]
                        + k2.z * qr[q][10] + k2.w * qr[q][11]
                        + k3.x * qr[q][12] + k3.y * qr[q][13]
                        + k3.z * qr[q][14] + k3.w * qr[q][15];
                sc[q][n] = d * 0.25f + msk[q][i];
            }
        }
    }
    __syncthreads();

    // ---- per-query softmax (wave wv -> query wv) ----
    {
        const int q = wv;
        float m = -INFINITY;
        for (int n = lane; n < N_; n += 64) m = fmaxf(m, sc[q][n]);
        #pragma unroll
        for (int off = 32; off > 0; off >>= 1) m = fmaxf(m, __shfl_xor(m, off));
        float s = 0.f;
        for (int n = lane; n < N_; n += 64) {
            const float e = __expf(sc[q][n] - m);
            sc[q][n] = e;
            s += e;
        }
        #pragma unroll
        for (int off = 32; off > 0; off >>= 1) s += __shfl_xor(s, off);
        if (lane == 0) invden_s[q] = 1.f / s;
    }
    __syncthreads();

    // ---- PV: shared V loads, 16 FMA per float4 ----
    {
        const int c = lane & 3, g = lane >> 2;
        const float* Vh = V2 + (size_t)(b * HEAD_ + h) * N_ * 16 + 4 * c;
        const int n0 = wv * 250;
        float4 a0 = {0.f, 0.f, 0.f, 0.f}, a1 = a0, a2 = a0, a3 = a0;
        #pragma unroll 4
        for (int i = 0; i < 16; ++i) {
            const int nn = 16 * i + g;
            if (nn < 250) {
                const int n = n0 + nn;
                const float4 v4 = *(const float4*)(Vh + (size_t)n * 16);
                const float w0 = sc[0][n], w1 = sc[1][n];
                const float w2 = sc[2][n], w3 = sc[3][n];
                a0.x = fmaf(w0, v4.x, a0.x); a0.y = fmaf(w0, v4.y, a0.y);
                a0.z = fmaf(w0, v4.z, a0.z); a0.w = fmaf(w0, v4.w, a0.w);
                a1.x = fmaf(w1, v4.x, a1.x); a1.y = fmaf(w1, v4.y, a1.y);
                a1.z = fmaf(w1, v4.z, a1.z); a1.w = fmaf(w1, v4.w, a1.w);
                a2.x = fmaf(w2, v4.x, a2.x); a2.y = fmaf(w2, v4.y, a2.y);
                a2.z = fmaf(w2, v4.z, a2.z); a2.w = fmaf(w2, v4.w, a2.w);
                a3.x = fmaf(w3, v4.x, a3.x); a3.y = fmaf(w3, v4.y, a3.y);
                a3.z = fmaf(w3, v4.z, a3.z); a3.w = fmaf(w3, v4.w, a3.w);
            }
        }
        #pragma unroll
        for (int off = 4; off <= 32; off <<= 1) {
            a0.x += __shfl_xor(a0.x, off); a0.y += __shfl_xor(a0.y, off);
            a0.z += __shfl_xor(a0.z, off); a0.w += __shfl_xor(a0.w, off);
            a1.x += __shfl_xor(a1.x, off); a1.y += __shfl_xor(a1.y, off);
            a1.z += __shfl_xor(a1.z, off); a1.w += __shfl_xor(a1.w, off);
            a2.x += __shfl_xor(a2.x, off); a2.y += __shfl_xor(a2.y, off);
            a2.z += __shfl_xor(a2.z, off); a2.w += __shfl_xor(a2.w, off);
            a3.x += __shfl_xor(a3.x, off); a3.y += __shfl_xor(a3.y, off);
            a3.z += __shfl_xor(a3.z, off); a3.w += __shfl_xor(a3.w, off);
        }
        if (g == 0) {
            *(float4*)&part_s[wv][0][4 * c] = a0;
            *(float4*)&part_s[wv][1][4 * c] = a1;
            *(float4*)&part_s[wv][2][4 * c] = a2;
            *(float4*)&part_s[wv][3][4 * c] = a3;
        }
    }
    __syncthreads();

    // ---- finalize: out_g[bp0+q][h*16+d] ----
    if (t < 64) {
        const int q = t >> 4, d = t & 15;
        const float s = part_s[0][q][d] + part_s[1][q][d]
                      + part_s[2][q][d] + part_s[3][q][d];
        out_g[(size_t)(bp0 + q) * 128 + h * 16 + d] = s * invden_s[q];
    }
}

// ---------------------------------------------------------------------------
// Kernel 3b: Wc matvec + pointer scores + blend + final softmax.
// grid = 1600. XCD swizzle: physical = (b&7) + 8*(pt + 25*(b>>3)) so all 25
// p-tiles of batch b share one XCD's L2 (en panel 512 KB resident).
// Pointer phase: en staged in LDS (32x132 padded) via coalesced float4 copy
// with register prefetch; 8 threads/row, mh chunk in registers.
// ---------------------------------------------------------------------------
__global__ __launch_bounds__(256) void ptr_epilogue(
    const float* __restrict__ out_g, const float* __restrict__ en,
    const float* __restrict__ Wc, const float* __restrict__ bc,
    const float* __restrict__ cur_dist, const float* __restrict__ ninf,
    const float* __restrict__ noise, float* __restrict__ probs)
{
    __shared__ __align__(16) float en_s[32 * 132];     // 32 rows, pad +4
    __shared__ __align__(16) float sc[QT][1008];
    __shared__ __align__(16) float out_s[QT][128];
    __shared__ __align__(16) float mh_s[QT][128];

    const int blk  = blockIdx.x;
    const int rX   = blk & 7;
    const int j9   = blk >> 3;           // 0..199
    const int pt   = j9 % 25;
    const int b    = (j9 / 25) * 8 + rX;
    const int bp0  = b * P_ + pt * QT;
    const int t    = threadIdx.x;
    const int lane = t & 63;
    const int wv   = t >> 6;

    if (t < 128)
        ((float4*)&out_s[0][0])[t] = ((const float4*)(out_g + (size_t)bp0 * 128))[t];
    __syncthreads();

    // ---- mh = out @ Wc + bc (each thread: 2 queries, 1 column) ----
    {
        const int e = t & 127, qh = t >> 7;
        float a0 = bc[e], a1 = a0;
        for (int i = 0; i < 128; ++i) {
            const float w = Wc[i * 128 + e];
            a0 = fmaf(out_s[qh][i], w, a0);
            a1 = fmaf(out_s[qh + 2][i], w, a1);
        }
        mh_s[qh][e] = a0;
        mh_s[qh + 2][e] = a1;
    }
    __syncthreads();

    // ---- hoist this thread's mh dim-chunk (16 dims) for all 4 q ----
    const int row = t >> 3, c = t & 7;       // 32 rows x 8 dim-chunks
    float4 mhr[QT][4];
    #pragma unroll
    for (int q = 0; q < QT; ++q)
        #pragma unroll
        for (int jj = 0; jj < 4; ++jj)
            mhr[q][jj] = *(const float4*)&mh_s[q][c * 16 + 4 * jj];

    // ---- pointer scores: LDS-staged en tiles, coalesced + reg prefetch ----
    const float* enb = en + (size_t)b * N_ * 128;
    float4 pre[4];
    {
        const float4* g = (const float4*)enb;
        #pragma unroll
        for (int k = 0; k < 4; ++k) pre[k] = g[t + 256 * k];
    }
    for (int n0 = 0; n0 < N_; n0 += 32) {
        const int rows = (N_ - n0 < 32) ? (N_ - n0) : 32;
        __syncthreads();                       // prev tile compute done
        #pragma unroll
        for (int k = 0; k < 4; ++k) {
            const int L = t + 256 * k;         // float4 linear idx in tile
            if (L < rows * 32)
                *(float4*)&en_s[(L >> 5) * 132 + (L & 31) * 4] = pre[k];
        }
        const int n1 = n0 + 32;
        if (n1 < N_) {
            const int rows1 = (N_ - n1 < 32) ? (N_ - n1) : 32;
            const float4* g = (const float4*)(enb + (size_t)n1 * 128);
            #pragma unroll
            for (int k = 0; k < 4; ++k) {
                const int L = t + 256 * k;
                if (L < rows1 * 32) pre[k] = g[L];
            }
        }
        __syncthreads();                       // LDS visible
        if (row < rows) {
            float acc[QT] = {0.f, 0.f, 0.f, 0.f};
            #pragma unroll
            for (int jj = 0; jj < 4; ++jj) {
                const float4 e4 = *(const float4*)&en_s[row * 132 + c * 16 + 4 * jj];
                #pragma unroll
                for (int q = 0; q < QT; ++q) {
                    acc[q] = fmaf(e4.x, mhr[q][jj].x, fmaf(e4.y, mhr[q][jj].y,
                             fmaf(e4.z, mhr[q][jj].z, fmaf(e4.w, mhr[q][jj].w,
                             acc[q]))));
                }
            }
            #pragma unroll
            for (int q = 0; q < QT; ++q) {
                float v = acc[q];
                v += __shfl_xor(v, 1);
                v += __shfl_xor(v, 2);
                v += __shfl_xor(v, 4);
                if (c == 0) sc[q][n0 + row] = v;
            }
        }
    }
    __syncthreads();

    // ---- blend + clip + mask + final softmax (wave wv -> query wv) ----
    {
        const int q  = wv;
        const int bp = bp0 + q;
        const float* cd = cur_dist + (size_t)bp * N_;
        const float* nz = noise    + (size_t)bp * N_;
        const float* nf = ninf     + (size_t)bp * N_;
        const float A   = (float)kA_d;
        const float Bc2 = (float)(1.0 - kA_d);

        float m = -INFINITY;
        for (int n = lane; n < N_; n += 64) {
            const float s2 = sc[q][n] / 11.3137085f;
            const float st = cd[n] + cd[n];
            const float rh = -logf(st + 1e-6f);
            const float s  = s2 + A * rh + Bc2 * nz[n];
            const float sm = 10.f * tanhf(s) + nf[n];
            sc[q][n] = sm;
            m = fmaxf(m, sm);
        }
        #pragma unroll
        for (int off = 32; off > 0; off >>= 1) m = fmaxf(m, __shfl_xor(m, off));

        float s = 0.f;
        for (int n = lane; n < N_; n += 64) {
            const float e = __expf(sc[q][n] - m);
            sc[q][n] = e;
            s += e;
        }
        #pragma unroll
        for (int off = 32; off > 0; off >>= 1) s += __shfl_xor(s, off);

        const float inv = 1.f / s;
        float* out = probs + (size_t)bp * N_;
        for (int n = lane; n < N_; n += 64) out[n] = sc[q][n] * inv;
    }
}

// ---------------------------------------------------------------------------
extern "C" void kernel_launch(void* const* d_in, const int* in_sizes, int n_in,
                              void* d_out, int out_size, void* d_ws, size_t ws_size,
                              hipStream_t stream)
{
    const float* eln      = (const float*)d_in[0];
    const float* load_    = (const float*)d_in[1];
    const float* time_    = (const float*)d_in[2];
    const float* cur_dist = (const float*)d_in[3];
    const float* ninf     = (const float*)d_in[4];
    const float* noise    = (const float*)d_in[5];
    const float* en       = (const float*)d_in[6];
    const float* Wq       = (const float*)d_in[7];
    const float* Wk       = (const float*)d_in[8];
    const float* Wv       = (const float*)d_in[9];
    const float* Wc       = (const float*)d_in[10];
    const float* bc       = (const float*)d_in[11];
    float* probs = (float*)d_out;

    float* K2    = (float*)d_ws;                         // B*H*N*16
    float* V2    = K2 + (size_t)B_ * HEAD_ * N_ * 16;    // B*H*N*16
    float* Q     = V2 + (size_t)B_ * HEAD_ * N_ * 16;    // B*P*128
    float* out_g = Q  + (size_t)B_ * P_ * 128;           // B*P*128

    kv_proj<<<(B_ * N_) / 32, 256, 0, stream>>>(en, Wk, Wv, K2, V2);
    q_proj<<<(B_ * P_) / 8, 128, 0, stream>>>(eln, load_, time_, Wq, Q);
    attn_heads<<<B_ * HEAD_ * (P_ / QT), 256, 0, stream>>>(K2, V2, Q, ninf, out_g);
    ptr_epilogue<<<(B_ * P_) / QT, 256, 0, stream>>>(out_g, en, Wc, bc,
                                                     cur_dist, ninf, noise, probs);
}

// Round 8
// 495.569 us; speedup vs baseline: 1.3581x; 1.3581x over previous
//
#include <hip/hip_runtime.h>
#include <hip/hip_bf16.h>

#define B_   64
#define P_   100
#define N_   1000
#define EMB_ 128
#define HEAD_ 8
#define QKV_ 16
#define QT   4          // queries per tile

constexpr double kTwoPowNeg18 = 3.814697265625e-06; // 2^-18 exact
constexpr double kA_d = 1.0 / (1.0 + kTwoPowNeg18);

// ---------------------------------------------------------------------------
// Kernel 1: K2/V2 = heads(en @ Wk/Wv) in [b][h][n][16] layout.
// 32 rows per block, 256 threads. e-operand read as b128 broadcasts.
// ---------------------------------------------------------------------------
__global__ __launch_bounds__(256) void kv_proj(
    const float* __restrict__ en, const float* __restrict__ Wk,
    const float* __restrict__ Wv, float* __restrict__ K2, float* __restrict__ V2)
{
    __shared__ __align__(16) float e_s[32][128];
    const int t = threadIdx.x;
    const int j = t & 127;
    const int half = t >> 7;
    const int r0 = blockIdx.x * 32;

    {
        const float4* src = (const float4*)(en + (size_t)r0 * 128);
        float4* dst = (float4*)&e_s[0][0];
        #pragma unroll
        for (int k = 0; k < 4; ++k) dst[t + 256 * k] = src[t + 256 * k];
    }
    __syncthreads();

    float ak[16], av[16];
    #pragma unroll
    for (int r = 0; r < 16; ++r) { ak[r] = 0.f; av[r] = 0.f; }

    const int rb = half * 16;
    for (int i4 = 0; i4 < 32; ++i4) {
        float wk4[4], wv4[4];
        #pragma unroll
        for (int c = 0; c < 4; ++c) {
            wk4[c] = Wk[(4 * i4 + c) * 128 + j];
            wv4[c] = Wv[(4 * i4 + c) * 128 + j];
        }
        #pragma unroll
        for (int r = 0; r < 16; ++r) {
            const float4 e4 = *(const float4*)&e_s[rb + r][4 * i4];
            ak[r] = fmaf(e4.x, wk4[0], fmaf(e4.y, wk4[1],
                    fmaf(e4.z, wk4[2], fmaf(e4.w, wk4[3], ak[r]))));
            av[r] = fmaf(e4.x, wv4[0], fmaf(e4.y, wv4[1],
                    fmaf(e4.z, wv4[2], fmaf(e4.w, wv4[3], av[r]))));
        }
    }

    const int h = j >> 4, d = j & 15;
    #pragma unroll
    for (int r = 0; r < 16; ++r) {
        const int row = r0 + rb + r;
        const int bb = row / N_;
        const int n = row - bb * N_;
        const size_t idx = ((size_t)(bb * HEAD_ + h) * N_ + n) * 16 + d;
        K2[idx] = ak[r];
        V2[idx] = av[r];
    }
}

// ---------------------------------------------------------------------------
// Kernel 2: Q = [eln | load | time] @ Wq   (rows = B*P = 6400, Wq is 130x128)
// ---------------------------------------------------------------------------
__global__ __launch_bounds__(128) void q_proj(
    const float* __restrict__ eln, const float* __restrict__ load_,
    const float* __restrict__ time_, const float* __restrict__ Wq,
    float* __restrict__ Q)
{
    __shared__ __align__(16) float e_s[8][132];
    const int j  = threadIdx.x;
    const int r0 = blockIdx.x * 8;

    #pragma unroll
    for (int r = 0; r < 8; ++r) {
        const int row = r0 + r;
        e_s[r][j] = eln[(size_t)row * 128 + j];
        if (j == 0) {
            e_s[r][128] = load_[row];
            e_s[r][129] = time_[row];
        }
    }
    __syncthreads();

    float a[8];
    #pragma unroll
    for (int r = 0; r < 8; ++r) a[r] = 0.f;

    for (int i4 = 0; i4 < 32; ++i4) {
        float w4[4];
        #pragma unroll
        for (int c = 0; c < 4; ++c) w4[c] = Wq[(4 * i4 + c) * 128 + j];
        #pragma unroll
        for (int r = 0; r < 8; ++r) {
            const float4 e4 = *(const float4*)&e_s[r][4 * i4];
            a[r] = fmaf(e4.x, w4[0], fmaf(e4.y, w4[1],
                   fmaf(e4.z, w4[2], fmaf(e4.w, w4[3], a[r]))));
        }
    }
    #pragma unroll
    for (int i = 128; i < 130; ++i) {
        const float w = Wq[i * 128 + j];
        #pragma unroll
        for (int r = 0; r < 8; ++r)
            a[r] = fmaf(e_s[r][i], w, a[r]);
    }

    #pragma unroll
    for (int r = 0; r < 8; ++r)
        Q[(size_t)(r0 + r) * 128 + j] = a[r];
}

// ---------------------------------------------------------------------------
// Kernel 3a: per-head attention. grid = B * HEAD * (P/QT) = 12800 blocks.
// XCD swizzle: physical = h + 8*(pt + 25*b)  => XCD (i%8) = h, b-major order,
// so the 25 blocks sharing one (b,h) K/V panel co-locate on one XCD's L2.
// ---------------------------------------------------------------------------
__global__ __launch_bounds__(256) void attn_heads(
    const float* __restrict__ K2, const float* __restrict__ V2,
    const float* __restrict__ Q, const float* __restrict__ ninf,
    float* __restrict__ out_g)
{
    __shared__ __align__(16) float sc[QT][1008];
    __shared__ __align__(16) float q_s[QT][16];
    __shared__ __align__(16) float part_s[4][QT][16];
    __shared__ float invden_s[QT];

    const int blk = blockIdx.x;
    const int h   = blk & 7;
    const int j9  = blk >> 3;          // 0..1599
    const int pt  = j9 % 25;
    const int b   = j9 / 25;
    const int bp0 = b * P_ + pt * QT;
    const int t    = threadIdx.x;
    const int lane = t & 63;
    const int wv   = t >> 6;

    if (t < 64) q_s[t >> 4][t & 15] =
        Q[(size_t)(bp0 + (t >> 4)) * 128 + h * 16 + (t & 15)];
    __syncthreads();

    float qr[QT][16];
    #pragma unroll
    for (int q = 0; q < QT; ++q)
        #pragma unroll
        for (int c = 0; c < 4; ++c)
            *(float4*)&qr[q][4 * c] = *(const float4*)&q_s[q][4 * c];

    // hoist masks for this thread's n's into registers
    const float* nf0 = ninf + (size_t)bp0 * N_;
    float msk[QT][4];
    #pragma unroll
    for (int i = 0; i < 4; ++i) {
        const int n = t + 256 * i;
        if (n < N_) {
            #pragma unroll
            for (int q = 0; q < QT; ++q) msk[q][i] = nf0[q * N_ + n];
        }
    }

    // ---- scores ----
    const float* Kh = K2 + (size_t)(b * HEAD_ + h) * N_ * 16;
    #pragma unroll
    for (int i = 0; i < 4; ++i) {
        const int n = t + 256 * i;
        if (n < N_) {
            const float4* kr = (const float4*)(Kh + (size_t)n * 16);
            const float4 k0 = kr[0], k1 = kr[1], k2 = kr[2], k3 = kr[3];
            #pragma unroll
            for (int q = 0; q < QT; ++q) {
                float d = k0.x * qr[q][0]  + k0.y * qr[q][1]
                        + k0.z * qr[q][2]  + k0.w * qr[q][3]
                        + k1.x * qr[q][4]  + k1.y * qr[q][5]
                        + k1.z * qr[q][6]  + k1.w * qr[q][7]
                        + k2.x * qr[q][8]  + k2.y * qr[q][9]
                        + k2.z * qr[q][10] + k2.w * qr[q][11]
                        + k3.x * qr[q][12] + k3.y * qr[q][13]
                        + k3.z * qr[q][14] + k3.w * qr[q][15];
                sc[q][n] = d * 0.25f + msk[q][i];
            }
        }
    }
    __syncthreads();

    // ---- per-query softmax (wave wv -> query wv) ----
    {
        const int q = wv;
        float m = -INFINITY;
        for (int n = lane; n < N_; n += 64) m = fmaxf(m, sc[q][n]);
        #pragma unroll
        for (int off = 32; off > 0; off >>= 1) m = fmaxf(m, __shfl_xor(m, off));
        float s = 0.f;
        for (int n = lane; n < N_; n += 64) {
            const float e = __expf(sc[q][n] - m);
            sc[q][n] = e;
            s += e;
        }
        #pragma unroll
        for (int off = 32; off > 0; off >>= 1) s += __shfl_xor(s, off);
        if (lane == 0) invden_s[q] = 1.f / s;
    }
    __syncthreads();

    // ---- PV: shared V loads, 16 FMA per float4 ----
    {
        const int c = lane & 3, g = lane >> 2;
        const float* Vh = V2 + (size_t)(b * HEAD_ + h) * N_ * 16 + 4 * c;
        const int n0 = wv * 250;
        float4 a0 = {0.f, 0.f, 0.f, 0.f}, a1 = a0, a2 = a0, a3 = a0;
        #pragma unroll 4
        for (int i = 0; i < 16; ++i) {
            const int nn = 16 * i + g;
            if (nn < 250) {
                const int n = n0 + nn;
                const float4 v4 = *(const float4*)(Vh + (size_t)n * 16);
                const float w0 = sc[0][n], w1 = sc[1][n];
                const float w2 = sc[2][n], w3 = sc[3][n];
                a0.x = fmaf(w0, v4.x, a0.x); a0.y = fmaf(w0, v4.y, a0.y);
                a0.z = fmaf(w0, v4.z, a0.z); a0.w = fmaf(w0, v4.w, a0.w);
                a1.x = fmaf(w1, v4.x, a1.x); a1.y = fmaf(w1, v4.y, a1.y);
                a1.z = fmaf(w1, v4.z, a1.z); a1.w = fmaf(w1, v4.w, a1.w);
                a2.x = fmaf(w2, v4.x, a2.x); a2.y = fmaf(w2, v4.y, a2.y);
                a2.z = fmaf(w2, v4.z, a2.z); a2.w = fmaf(w2, v4.w, a2.w);
                a3.x = fmaf(w3, v4.x, a3.x); a3.y = fmaf(w3, v4.y, a3.y);
                a3.z = fmaf(w3, v4.z, a3.z); a3.w = fmaf(w3, v4.w, a3.w);
            }
        }
        #pragma unroll
        for (int off = 4; off <= 32; off <<= 1) {
            a0.x += __shfl_xor(a0.x, off); a0.y += __shfl_xor(a0.y, off);
            a0.z += __shfl_xor(a0.z, off); a0.w += __shfl_xor(a0.w, off);
            a1.x += __shfl_xor(a1.x, off); a1.y += __shfl_xor(a1.y, off);
            a1.z += __shfl_xor(a1.z, off); a1.w += __shfl_xor(a1.w, off);
            a2.x += __shfl_xor(a2.x, off); a2.y += __shfl_xor(a2.y, off);
            a2.z += __shfl_xor(a2.z, off); a2.w += __shfl_xor(a2.w, off);
            a3.x += __shfl_xor(a3.x, off); a3.y += __shfl_xor(a3.y, off);
            a3.z += __shfl_xor(a3.z, off); a3.w += __shfl_xor(a3.w, off);
        }
        if (g == 0) {
            *(float4*)&part_s[wv][0][4 * c] = a0;
            *(float4*)&part_s[wv][1][4 * c] = a1;
            *(float4*)&part_s[wv][2][4 * c] = a2;
            *(float4*)&part_s[wv][3][4 * c] = a3;
        }
    }
    __syncthreads();

    // ---- finalize: out_g[bp0+q][h*16+d] ----
    if (t < 64) {
        const int q = t >> 4, d = t & 15;
        const float s = part_s[0][q][d] + part_s[1][q][d]
                      + part_s[2][q][d] + part_s[3][q][d];
        out_g[(size_t)(bp0 + q) * 128 + h * 16 + d] = s * invden_s[q];
    }
}

// ---------------------------------------------------------------------------
// Kernel 3b: Wc matvec + pointer scores + blend + final softmax.
// grid = 1600. XCD swizzle: all 25 p-tiles of batch b share one XCD's L2
// (en panel 512 KB resident). Pointer phase: wave-cooperative, 16 lanes per
// en row (lane k owns dims 8k..8k+8 of mh in regs), two b128 loads per row,
// 4-step shuffle reduce. No registers live across barriers -> no spills.
// ---------------------------------------------------------------------------
__global__ __launch_bounds__(256) void ptr_epilogue(
    const float* __restrict__ out_g, const float* __restrict__ en,
    const float* __restrict__ Wc, const float* __restrict__ bc,
    const float* __restrict__ cur_dist, const float* __restrict__ ninf,
    const float* __restrict__ noise, float* __restrict__ probs)
{
    __shared__ __align__(16) float sc[QT][1008];
    __shared__ __align__(16) float out_s[QT][128];
    __shared__ __align__(16) float mh_s[QT][128];

    const int blk  = blockIdx.x;
    const int rX   = blk & 7;
    const int j9   = blk >> 3;           // 0..199
    const int pt   = j9 % 25;
    const int b    = (j9 / 25) * 8 + rX;
    const int bp0  = b * P_ + pt * QT;
    const int t    = threadIdx.x;
    const int lane = t & 63;
    const int wv   = t >> 6;

    if (t < 128)
        ((float4*)&out_s[0][0])[t] = ((const float4*)(out_g + (size_t)bp0 * 128))[t];
    __syncthreads();

    // ---- mh = out @ Wc + bc (each thread: 2 queries, 1 column) ----
    {
        const int e = t & 127, qh = t >> 7;
        float a0 = bc[e], a1 = a0;
        for (int i = 0; i < 128; ++i) {
            const float w = Wc[i * 128 + e];
            a0 = fmaf(out_s[qh][i], w, a0);
            a1 = fmaf(out_s[qh + 2][i], w, a1);
        }
        mh_s[qh][e] = a0;
        mh_s[qh + 2][e] = a1;
    }
    __syncthreads();

    // ---- pointer scores: 16 lanes per row, mh chunk in 32 VGPRs ----
    {
        const int k16 = lane & 15, g = lane >> 4;
        float4 mh0[QT], mh1[QT];
        #pragma unroll
        for (int q = 0; q < QT; ++q) {
            mh0[q] = *(const float4*)&mh_s[q][k16 * 8];
            mh1[q] = *(const float4*)&mh_s[q][k16 * 8 + 4];
        }
        const float* enb = en + (size_t)b * N_ * 128;
        // wave wv handles rows {4*wv + 16*i + g}; covers all n in [0,1000)
        for (int nb = 4 * wv; nb < N_; nb += 16) {
            const int n = nb + g;                  // nb%4==0, nb<=996 -> n<=999
            const float4* er = (const float4*)(enb + (size_t)n * 128 + k16 * 8);
            const float4 e0 = er[0], e1 = er[1];
            float acc[QT];
            #pragma unroll
            for (int q = 0; q < QT; ++q) {
                acc[q] = e0.x * mh0[q].x + e0.y * mh0[q].y
                       + e0.z * mh0[q].z + e0.w * mh0[q].w
                       + e1.x * mh1[q].x + e1.y * mh1[q].y
                       + e1.z * mh1[q].z + e1.w * mh1[q].w;
            }
            #pragma unroll
            for (int q = 0; q < QT; ++q) {
                float v = acc[q];
                v += __shfl_xor(v, 1);
                v += __shfl_xor(v, 2);
                v += __shfl_xor(v, 4);
                v += __shfl_xor(v, 8);
                if (k16 == 0) sc[q][n] = v;
            }
        }
    }
    __syncthreads();

    // ---- blend + clip + mask + final softmax (wave wv -> query wv) ----
    {
        const int q  = wv;
        const int bp = bp0 + q;
        const float* cd = cur_dist + (size_t)bp * N_;
        const float* nz = noise    + (size_t)bp * N_;
        const float* nf = ninf     + (size_t)bp * N_;
        const float A   = (float)kA_d;
        const float Bc2 = (float)(1.0 - kA_d);

        float m = -INFINITY;
        for (int n = lane; n < N_; n += 64) {
            const float s2 = sc[q][n] / 11.3137085f;
            const float st = cd[n] + cd[n];
            const float rh = -logf(st + 1e-6f);
            const float s  = s2 + A * rh + Bc2 * nz[n];
            const float sm = 10.f * tanhf(s) + nf[n];
            sc[q][n] = sm;
            m = fmaxf(m, sm);
        }
        #pragma unroll
        for (int off = 32; off > 0; off >>= 1) m = fmaxf(m, __shfl_xor(m, off));

        float s = 0.f;
        for (int n = lane; n < N_; n += 64) {
            const float e = __expf(sc[q][n] - m);
            sc[q][n] = e;
            s += e;
        }
        #pragma unroll
        for (int off = 32; off > 0; off >>= 1) s += __shfl_xor(s, off);

        const float inv = 1.f / s;
        float* out = probs + (size_t)bp * N_;
        for (int n = lane; n < N_; n += 64) out[n] = sc[q][n] * inv;
    }
}

// ---------------------------------------------------------------------------
extern "C" void kernel_launch(void* const* d_in, const int* in_sizes, int n_in,
                              void* d_out, int out_size, void* d_ws, size_t ws_size,
                              hipStream_t stream)
{
    const float* eln      = (const float*)d_in[0];
    const float* load_    = (const float*)d_in[1];
    const float* time_    = (const float*)d_in[2];
    const float* cur_dist = (const float*)d_in[3];
    const float* ninf     = (const float*)d_in[4];
    const float* noise    = (const float*)d_in[5];
    const float* en       = (const float*)d_in[6];
    const float* Wq       = (const float*)d_in[7];
    const float* Wk       = (const float*)d_in[8];
    const float* Wv       = (const float*)d_in[9];
    const float* Wc       = (const float*)d_in[10];
    const float* bc       = (const float*)d_in[11];
    float* probs = (float*)d_out;

    float* K2    = (float*)d_ws;                         // B*H*N*16
    float* V2    = K2 + (size_t)B_ * HEAD_ * N_ * 16;    // B*H*N*16
    float* Q     = V2 + (size_t)B_ * HEAD_ * N_ * 16;    // B*P*128
    float* out_g = Q  + (size_t)B_ * P_ * 128;           // B*P*128

    kv_proj<<<(B_ * N_) / 32, 256, 0, stream>>>(en, Wk, Wv, K2, V2);
    q_proj<<<(B_ * P_) / 8, 128, 0, stream>>>(eln, load_, time_, Wq, Q);
    attn_heads<<<B_ * HEAD_ * (P_ / QT), 256, 0, stream>>>(K2, V2, Q, ninf, out_g);
    ptr_epilogue<<<(B_ * P_) / QT, 256, 0, stream>>>(out_g, en, Wc, bc,
                                                     cur_dist, ninf, noise, probs);
}

// Round 9
// 488.215 us; speedup vs baseline: 1.3785x; 1.0151x over previous
//
#include <hip/hip_runtime.h>
#include <hip/hip_bf16.h>

#define B_   64
#define P_   100
#define N_   1000
#define EMB_ 128
#define HEAD_ 8
#define QKV_ 16
#define QT   4          // queries per tile

constexpr double kTwoPowNeg18 = 3.814697265625e-06; // 2^-18 exact
constexpr double kA_d = 1.0 / (1.0 + kTwoPowNeg18);

// Keep a float4 pinned in VGPRs (prevents the compiler sinking its LDS load
// into a loop). Zero instructions emitted.
#define KEEP4(v) asm volatile("" : "+v"((v).x), "+v"((v).y), "+v"((v).z), "+v"((v).w))

// ---------------------------------------------------------------------------
// Kernel 1: K2/V2 = heads(en @ Wk/Wv) in [b][h][n][16] layout.
// 64 rows per block, 256 threads; thread (grp = t>>6, j = t&63) computes
// 16 rows x cols {j, j+64} x {K,V}: 256 FMA per 16 broadcast ds_read_b128.
// ---------------------------------------------------------------------------
__global__ __launch_bounds__(256) void kv_proj(
    const float* __restrict__ en, const float* __restrict__ Wk,
    const float* __restrict__ Wv, float* __restrict__ K2, float* __restrict__ V2)
{
    __shared__ __align__(16) float e_s[64][128];
    const int t  = threadIdx.x;
    const int j  = t & 63;
    const int rb = (t >> 6) * 16;
    const int r0 = blockIdx.x * 64;

    {
        const float4* src = (const float4*)(en + (size_t)r0 * 128);
        float4* dst = (float4*)&e_s[0][0];
        #pragma unroll
        for (int k = 0; k < 8; ++k) dst[t + 256 * k] = src[t + 256 * k];
    }
    __syncthreads();

    float ak0[16], ak1[16], av0[16], av1[16];
    #pragma unroll
    for (int r = 0; r < 16; ++r) { ak0[r] = 0.f; ak1[r] = 0.f; av0[r] = 0.f; av1[r] = 0.f; }

    for (int i4 = 0; i4 < 32; ++i4) {
        float wk0[4], wk1[4], wv0[4], wv1[4];
        #pragma unroll
        for (int c = 0; c < 4; ++c) {
            const int rowi = (4 * i4 + c) * 128;
            wk0[c] = Wk[rowi + j];
            wk1[c] = Wk[rowi + j + 64];
            wv0[c] = Wv[rowi + j];
            wv1[c] = Wv[rowi + j + 64];
        }
        #pragma unroll
        for (int r = 0; r < 16; ++r) {
            const float4 e4 = *(const float4*)&e_s[rb + r][4 * i4];
            ak0[r] = fmaf(e4.x, wk0[0], fmaf(e4.y, wk0[1],
                     fmaf(e4.z, wk0[2], fmaf(e4.w, wk0[3], ak0[r]))));
            ak1[r] = fmaf(e4.x, wk1[0], fmaf(e4.y, wk1[1],
                     fmaf(e4.z, wk1[2], fmaf(e4.w, wk1[3], ak1[r]))));
            av0[r] = fmaf(e4.x, wv0[0], fmaf(e4.y, wv0[1],
                     fmaf(e4.z, wv0[2], fmaf(e4.w, wv0[3], av0[r]))));
            av1[r] = fmaf(e4.x, wv1[0], fmaf(e4.y, wv1[1],
                     fmaf(e4.z, wv1[2], fmaf(e4.w, wv1[3], av1[r]))));
        }
    }

    const int h0 = j >> 4, d0 = j & 15;            // col j
    const int h1 = (j + 64) >> 4, d1 = j & 15;     // col j+64 (d same since 64%16==0)
    #pragma unroll
    for (int r = 0; r < 16; ++r) {
        const int row = r0 + rb + r;
        const int bb = row / N_;
        const int n = row - bb * N_;
        const size_t base = ((size_t)bb * HEAD_ * N_ + n) * 16;
        K2[base + (size_t)h0 * N_ * 16 + d0] = ak0[r];
        K2[base + (size_t)h1 * N_ * 16 + d1] = ak1[r];
        V2[base + (size_t)h0 * N_ * 16 + d0] = av0[r];
        V2[base + (size_t)h1 * N_ * 16 + d1] = av1[r];
    }
}

// ---------------------------------------------------------------------------
// Kernel 2: Q = [eln | load | time] @ Wq   (rows = B*P = 6400, Wq is 130x128)
// ---------------------------------------------------------------------------
__global__ __launch_bounds__(128) void q_proj(
    const float* __restrict__ eln, const float* __restrict__ load_,
    const float* __restrict__ time_, const float* __restrict__ Wq,
    float* __restrict__ Q)
{
    __shared__ __align__(16) float e_s[8][132];
    const int j  = threadIdx.x;
    const int r0 = blockIdx.x * 8;

    #pragma unroll
    for (int r = 0; r < 8; ++r) {
        const int row = r0 + r;
        e_s[r][j] = eln[(size_t)row * 128 + j];
        if (j == 0) {
            e_s[r][128] = load_[row];
            e_s[r][129] = time_[row];
        }
    }
    __syncthreads();

    float a[8];
    #pragma unroll
    for (int r = 0; r < 8; ++r) a[r] = 0.f;

    for (int i4 = 0; i4 < 32; ++i4) {
        float w4[4];
        #pragma unroll
        for (int c = 0; c < 4; ++c) w4[c] = Wq[(4 * i4 + c) * 128 + j];
        #pragma unroll
        for (int r = 0; r < 8; ++r) {
            const float4 e4 = *(const float4*)&e_s[r][4 * i4];
            a[r] = fmaf(e4.x, w4[0], fmaf(e4.y, w4[1],
                   fmaf(e4.z, w4[2], fmaf(e4.w, w4[3], a[r]))));
        }
    }
    #pragma unroll
    for (int i = 128; i < 130; ++i) {
        const float w = Wq[i * 128 + j];
        #pragma unroll
        for (int r = 0; r < 8; ++r)
            a[r] = fmaf(e_s[r][i], w, a[r]);
    }

    #pragma unroll
    for (int r = 0; r < 8; ++r)
        Q[(size_t)(r0 + r) * 128 + j] = a[r];
}

// ---------------------------------------------------------------------------
// Kernel 3a: per-head attention. grid = B * HEAD * (P/QT) = 12800 blocks.
// XCD swizzle: physical = h + 8*(pt + 25*b)  => XCD (i%8) = h, b-major order,
// so the 25 blocks sharing one (b,h) K/V panel co-locate on one XCD's L2.
// ---------------------------------------------------------------------------
__global__ __launch_bounds__(256) void attn_heads(
    const float* __restrict__ K2, const float* __restrict__ V2,
    const float* __restrict__ Q, const float* __restrict__ ninf,
    float* __restrict__ out_g)
{
    __shared__ __align__(16) float sc[QT][1008];
    __shared__ __align__(16) float q_s[QT][16];
    __shared__ __align__(16) float part_s[4][QT][16];
    __shared__ float invden_s[QT];

    const int blk = blockIdx.x;
    const int h   = blk & 7;
    const int j9  = blk >> 3;          // 0..1599
    const int pt  = j9 % 25;
    const int b   = j9 / 25;
    const int bp0 = b * P_ + pt * QT;
    const int t    = threadIdx.x;
    const int lane = t & 63;
    const int wv   = t >> 6;

    if (t < 64) q_s[t >> 4][t & 15] =
        Q[(size_t)(bp0 + (t >> 4)) * 128 + h * 16 + (t & 15)];
    __syncthreads();

    float qr[QT][16];
    #pragma unroll
    for (int q = 0; q < QT; ++q)
        #pragma unroll
        for (int c = 0; c < 4; ++c)
            *(float4*)&qr[q][4 * c] = *(const float4*)&q_s[q][4 * c];

    // hoist masks for this thread's n's into registers
    const float* nf0 = ninf + (size_t)bp0 * N_;
    float msk[QT][4];
    #pragma unroll
    for (int i = 0; i < 4; ++i) {
        const int n = t + 256 * i;
        if (n < N_) {
            #pragma unroll
            for (int q = 0; q < QT; ++q) msk[q][i] = nf0[q * N_ + n];
        }
    }

    // ---- scores ----
    const float* Kh = K2 + (size_t)(b * HEAD_ + h) * N_ * 16;
    #pragma unroll
    for (int i = 0; i < 4; ++i) {
        const int n = t + 256 * i;
        if (n < N_) {
            const float4* kr = (const float4*)(Kh + (size_t)n * 16);
            const float4 k0 = kr[0], k1 = kr[1], k2 = kr[2], k3 = kr[3];
            #pragma unroll
            for (int q = 0; q < QT; ++q) {
                float d = k0.x * qr[q][0]  + k0.y * qr[q][1]
                        + k0.z * qr[q][2]  + k0.w * qr[q][3]
                        + k1.x * qr[q][4]  + k1.y * qr[q][5]
                        + k1.z * qr[q][6]  + k1.w * qr[q][7]
                        + k2.x * qr[q][8]  + k2.y * qr[q][9]
                        + k2.z * qr[q][10] + k2.w * qr[q][11]
                        + k3.x * qr[q][12] + k3.y * qr[q][13]
                        + k3.z * qr[q][14] + k3.w * qr[q][15];
                sc[q][n] = d * 0.25f + msk[q][i];
            }
        }
    }
    __syncthreads();

    // ---- per-query softmax (wave wv -> query wv) ----
    {
        const int q = wv;
        float m = -INFINITY;
        for (int n = lane; n < N_; n += 64) m = fmaxf(m, sc[q][n]);
        #pragma unroll
        for (int off = 32; off > 0; off >>= 1) m = fmaxf(m, __shfl_xor(m, off));
        float s = 0.f;
        for (int n = lane; n < N_; n += 64) {
            const float e = __expf(sc[q][n] - m);
            sc[q][n] = e;
            s += e;
        }
        #pragma unroll
        for (int off = 32; off > 0; off >>= 1) s += __shfl_xor(s, off);
        if (lane == 0) invden_s[q] = 1.f / s;
    }
    __syncthreads();

    // ---- PV: shared V loads, 16 FMA per float4 ----
    {
        const int c = lane & 3, g = lane >> 2;
        const float* Vh = V2 + (size_t)(b * HEAD_ + h) * N_ * 16 + 4 * c;
        const int n0 = wv * 250;
        float4 a0 = {0.f, 0.f, 0.f, 0.f}, a1 = a0, a2 = a0, a3 = a0;
        #pragma unroll 4
        for (int i = 0; i < 16; ++i) {
            const int nn = 16 * i + g;
            if (nn < 250) {
                const int n = n0 + nn;
                const float4 v4 = *(const float4*)(Vh + (size_t)n * 16);
                const float w0 = sc[0][n], w1 = sc[1][n];
                const float w2 = sc[2][n], w3 = sc[3][n];
                a0.x = fmaf(w0, v4.x, a0.x); a0.y = fmaf(w0, v4.y, a0.y);
                a0.z = fmaf(w0, v4.z, a0.z); a0.w = fmaf(w0, v4.w, a0.w);
                a1.x = fmaf(w1, v4.x, a1.x); a1.y = fmaf(w1, v4.y, a1.y);
                a1.z = fmaf(w1, v4.z, a1.z); a1.w = fmaf(w1, v4.w, a1.w);
                a2.x = fmaf(w2, v4.x, a2.x); a2.y = fmaf(w2, v4.y, a2.y);
                a2.z = fmaf(w2, v4.z, a2.z); a2.w = fmaf(w2, v4.w, a2.w);
                a3.x = fmaf(w3, v4.x, a3.x); a3.y = fmaf(w3, v4.y, a3.y);
                a3.z = fmaf(w3, v4.z, a3.z); a3.w = fmaf(w3, v4.w, a3.w);
            }
        }
        #pragma unroll
        for (int off = 4; off <= 32; off <<= 1) {
            a0.x += __shfl_xor(a0.x, off); a0.y += __shfl_xor(a0.y, off);
            a0.z += __shfl_xor(a0.z, off); a0.w += __shfl_xor(a0.w, off);
            a1.x += __shfl_xor(a1.x, off); a1.y += __shfl_xor(a1.y, off);
            a1.z += __shfl_xor(a1.z, off); a1.w += __shfl_xor(a1.w, off);
            a2.x += __shfl_xor(a2.x, off); a2.y += __shfl_xor(a2.y, off);
            a2.z += __shfl_xor(a2.z, off); a2.w += __shfl_xor(a2.w, off);
            a3.x += __shfl_xor(a3.x, off); a3.y += __shfl_xor(a3.y, off);
            a3.z += __shfl_xor(a3.z, off); a3.w += __shfl_xor(a3.w, off);
        }
        if (g == 0) {
            *(float4*)&part_s[wv][0][4 * c] = a0;
            *(float4*)&part_s[wv][1][4 * c] = a1;
            *(float4*)&part_s[wv][2][4 * c] = a2;
            *(float4*)&part_s[wv][3][4 * c] = a3;
        }
    }
    __syncthreads();

    // ---- finalize: out_g[bp0+q][h*16+d] ----
    if (t < 64) {
        const int q = t >> 4, d = t & 15;
        const float s = part_s[0][q][d] + part_s[1][q][d]
                      + part_s[2][q][d] + part_s[3][q][d];
        out_g[(size_t)(bp0 + q) * 128 + h * 16 + d] = s * invden_s[q];
    }
}

// ---------------------------------------------------------------------------
// Kernel 3b: Wc matvec + pointer scores + blend + final softmax.
// grid = 1600. XCD swizzle: all 25 p-tiles of batch b share one XCD's L2.
// Pointer phase: 16 lanes per en row, mh chunk PINNED in 32 VGPRs (KEEP4
// stops the compiler sinking the LDS loads into the loop — R8 showed
// VGPR=28, i.e. 8 ds_reads re-issued per iteration).
// ---------------------------------------------------------------------------
__global__ __launch_bounds__(256) void ptr_epilogue(
    const float* __restrict__ out_g, const float* __restrict__ en,
    const float* __restrict__ Wc, const float* __restrict__ bc,
    const float* __restrict__ cur_dist, const float* __restrict__ ninf,
    const float* __restrict__ noise, float* __restrict__ probs)
{
    __shared__ __align__(16) float sc[QT][1008];
    __shared__ __align__(16) float out_s[QT][128];
    __shared__ __align__(16) float mh_s[QT][128];

    const int blk  = blockIdx.x;
    const int rX   = blk & 7;
    const int j9   = blk >> 3;           // 0..199
    const int pt   = j9 % 25;
    const int b    = (j9 / 25) * 8 + rX;
    const int bp0  = b * P_ + pt * QT;
    const int t    = threadIdx.x;
    const int lane = t & 63;
    const int wv   = t >> 6;

    if (t < 128)
        ((float4*)&out_s[0][0])[t] = ((const float4*)(out_g + (size_t)bp0 * 128))[t];
    __syncthreads();

    // ---- mh = out @ Wc + bc (each thread: 2 queries, 1 column) ----
    {
        const int e = t & 127, qh = t >> 7;
        float a0 = bc[e], a1 = a0;
        for (int i = 0; i < 128; ++i) {
            const float w = Wc[i * 128 + e];
            a0 = fmaf(out_s[qh][i], w, a0);
            a1 = fmaf(out_s[qh + 2][i], w, a1);
        }
        mh_s[qh][e] = a0;
        mh_s[qh + 2][e] = a1;
    }
    __syncthreads();

    // ---- pointer scores: 16 lanes per row, mh chunk pinned in 32 VGPRs ----
    {
        const int k16 = lane & 15, g = lane >> 4;
        float4 mh0[QT], mh1[QT];
        #pragma unroll
        for (int q = 0; q < QT; ++q) {
            mh0[q] = *(const float4*)&mh_s[q][k16 * 8];
            mh1[q] = *(const float4*)&mh_s[q][k16 * 8 + 4];
            KEEP4(mh0[q]);
            KEEP4(mh1[q]);
        }
        const float* enb = en + (size_t)b * N_ * 128;
        // wave wv handles rows {4*wv + 16*i + g}; covers all n in [0,1000)
        #pragma unroll 2
        for (int nb = 4 * wv; nb < N_; nb += 16) {
            const int n = nb + g;                  // nb%4==0, nb<=996 -> n<=999
            const float4* er = (const float4*)(enb + (size_t)n * 128 + k16 * 8);
            const float4 e0 = er[0], e1 = er[1];
            float acc[QT];
            #pragma unroll
            for (int q = 0; q < QT; ++q) {
                acc[q] = e0.x * mh0[q].x + e0.y * mh0[q].y
                       + e0.z * mh0[q].z + e0.w * mh0[q].w
                       + e1.x * mh1[q].x + e1.y * mh1[q].y
                       + e1.z * mh1[q].z + e1.w * mh1[q].w;
            }
            #pragma unroll
            for (int q = 0; q < QT; ++q) {
                float v = acc[q];
                v += __shfl_xor(v, 1);
                v += __shfl_xor(v, 2);
                v += __shfl_xor(v, 4);
                v += __shfl_xor(v, 8);
                if (k16 == 0) sc[q][n] = v;
            }
        }
    }
    __syncthreads();

    // ---- blend + clip + mask + final softmax (wave wv -> query wv) ----
    {
        const int q  = wv;
        const int bp = bp0 + q;
        const float* cd = cur_dist + (size_t)bp * N_;
        const float* nz = noise    + (size_t)bp * N_;
        const float* nf = ninf     + (size_t)bp * N_;
        const float A   = (float)kA_d;
        const float Bc2 = (float)(1.0 - kA_d);

        float m = -INFINITY;
        for (int n = lane; n < N_; n += 64) {
            const float s2 = sc[q][n] / 11.3137085f;
            const float st = cd[n] + cd[n];
            const float rh = -logf(st + 1e-6f);
            const float s  = s2 + A * rh + Bc2 * nz[n];
            const float sm = 10.f * tanhf(s) + nf[n];
            sc[q][n] = sm;
            m = fmaxf(m, sm);
        }
        #pragma unroll
        for (int off = 32; off > 0; off >>= 1) m = fmaxf(m, __shfl_xor(m, off));

        float s = 0.f;
        for (int n = lane; n < N_; n += 64) {
            const float e = __expf(sc[q][n] - m);
            sc[q][n] = e;
            s += e;
        }
        #pragma unroll
        for (int off = 32; off > 0; off >>= 1) s += __shfl_xor(s, off);

        const float inv = 1.f / s;
        float* out = probs + (size_t)bp * N_;
        for (int n = lane; n < N_; n += 64) out[n] = sc[q][n] * inv;
    }
}

// ---------------------------------------------------------------------------
extern "C" void kernel_launch(void* const* d_in, const int* in_sizes, int n_in,
                              void* d_out, int out_size, void* d_ws, size_t ws_size,
                              hipStream_t stream)
{
    const float* eln      = (const float*)d_in[0];
    const float* load_    = (const float*)d_in[1];
    const float* time_    = (const float*)d_in[2];
    const float* cur_dist = (const float*)d_in[3];
    const float* ninf     = (const float*)d_in[4];
    const float* noise    = (const float*)d_in[5];
    const float* en       = (const float*)d_in[6];
    const float* Wq       = (const float*)d_in[7];
    const float* Wk       = (const float*)d_in[8];
    const float* Wv       = (const float*)d_in[9];
    const float* Wc       = (const float*)d_in[10];
    const float* bc       = (const float*)d_in[11];
    float* probs = (float*)d_out;

    float* K2    = (float*)d_ws;                         // B*H*N*16
    float* V2    = K2 + (size_t)B_ * HEAD_ * N_ * 16;    // B*H*N*16
    float* Q     = V2 + (size_t)B_ * HEAD_ * N_ * 16;    // B*P*128
    float* out_g = Q  + (size_t)B_ * P_ * 128;           // B*P*128

    kv_proj<<<(B_ * N_) / 64, 256, 0, stream>>>(en, Wk, Wv, K2, V2);
    q_proj<<<(B_ * P_) / 8, 128, 0, stream>>>(eln, load_, time_, Wq, Q);
    attn_heads<<<B_ * HEAD_ * (P_ / QT), 256, 0, stream>>>(K2, V2, Q, ninf, out_g);
    ptr_epilogue<<<(B_ * P_) / QT, 256, 0, stream>>>(out_g, en, Wc, bc,
                                                     cur_dist, ninf, noise, probs);
}